// Round 7
// baseline (148.395 us; speedup 1.0000x reference)
//
#include <hip/hip_runtime.h>

// ---------------- problem constants ----------------
#define F2      254
#define NPIX    (F2 * F2)        // 64516 conv2 output pixels
#define KGT     16
#define GWC     (1.0f / 1024.0f) // gw == gh == 1/IMG

typedef __attribute__((ext_vector_type(8))) short bf16x8;
typedef __attribute__((ext_vector_type(4))) float f32x4;

// ---------------- static device storage ----------------
__device__ unsigned short g_feats[256 * 256 * 128];  // conv1 out, bf16, 16.78 MB
__device__ unsigned short g_W2s[36 * 3 * 64 * 8];    // combined conv2 weights, bf16, MFMA-B swizzled
__device__ float          g_b2[48];
// cross-call state: statically initialized for the FIRST call; the finalizing
// block of k_convC_loss resets all three for the NEXT call.
__device__ float          g_acc[4] = {0.0f, 0.0f, 0.0f, 0.0f};
__device__ unsigned       g_keys[KGT] = {
    0x407FFFFFu, 0x407FFFFFu, 0x407FFFFFu, 0x407FFFFFu,
    0x407FFFFFu, 0x407FFFFFu, 0x407FFFFFu, 0x407FFFFFu,
    0x407FFFFFu, 0x407FFFFFu, 0x407FFFFFu, 0x407FFFFFu,
    0x407FFFFFu, 0x407FFFFFu, 0x407FFFFFu, 0x407FFFFFu};   // enc(-1.0f)
__device__ unsigned       g_done = 0u;

__device__ __forceinline__ float b2f(unsigned short h) {
    return __uint_as_float(((unsigned)h) << 16);
}
__device__ __forceinline__ unsigned short f2b(float f) {
    unsigned u = __float_as_uint(f);
    unsigned r = (u + 0x7FFFu + ((u >> 16) & 1u)) >> 16;
    return (unsigned short)r;
}

// ---------------- shared IoU16: ONE inlined expression tree -> bit-exact across callers ----------------
__device__ __forceinline__ void iou16(float x1, float y1, float x2, float y2,
                                      const float* __restrict__ gt, float* __restrict__ v) {
    float s1 = (x2 - x1 + GWC) * (y2 - y1 + GWC);
#pragma unroll
    for (int k = 0; k < KGT; ++k) {
        float gx1 = gt[k * 4 + 0], gy1 = gt[k * 4 + 1];
        float gx2 = gt[k * 4 + 2], gy2 = gt[k * 4 + 3];
        float s2 = (gx2 - gx1 + GWC) * (gy2 - gy1 + GWC);
        float xa = fmaxf(x1, gx1), ya = fmaxf(y1, gy1);
        float xb = fminf(x2, gx2), yb = fminf(y2, gy2);
        float iw = fmaxf(xb - xa + GWC, 0.0f);
        float ih = fmaxf(yb - ya + GWC, 0.0f);
        float inter = iw * ih;
        v[k] = inter / (s1 + s2 - inter);
    }
}

// per-type half extents (uniform within a type-major block)
__device__ __forceinline__ void type_extent(int a, float* hw, float* hh) {
    int ri = a / 3, si = a - ri * 3;
    float rat = (ri == 0) ? 0.5f : (ri == 1) ? 1.0f : 2.0f;
    float scl = (si == 0) ? 0.2f : (si == 1) ? 0.4f : 0.7f;
    float rs = sqrtf(rat);
    *hw = scl * rs * 0.5f;
    *hh = scl / rs * 0.5f;
}

// helper: load 8 consecutive im2col k-values (k-order = r*12+q) of one pixel as bf16x8
__device__ __forceinline__ bf16x8 ld_a8(const float* ib, int kbase) {
    int r0 = kbase / 12, q0 = kbase - r0 * 12;
    unsigned short a8[8];
    float4 f0 = *(const float4*)(ib + (size_t)r0 * 3072 + q0);
    int k4 = kbase + 4;
    int r1 = k4 / 12, q1 = k4 - r1 * 12;
    float4 f1 = *(const float4*)(ib + (size_t)r1 * 3072 + q1);
    a8[0] = f2b(f0.x); a8[1] = f2b(f0.y); a8[2] = f2b(f0.z); a8[3] = f2b(f0.w);
    a8[4] = f2b(f1.x); a8[5] = f2b(f1.y); a8[6] = f2b(f1.z); a8[7] = f2b(f1.w);
    return *(bf16x8*)a8;
}

// ---------------- k_front: conv1(MFMA, in-block Wb stage) + W2 combine + gtmax ----------------
// EXACT R2 body (measured 125.7 us total): roles in PARALLEL blocks.
// R6 lesson: folding roles into conv1 blocks serializes them in-block and the
// stragglers set kernel duration (-15 us). Keep parallel-block layout.
// blocks [0,1024)    : conv1 (per-block Wb LDS stage, XCD-banded)
// blocks [1024,1312) : W2 combine (two 128-oc passes)
// blocks [1312,1600) : gtmax (9 x 32 units)
__global__ __launch_bounds__(256) void k_front(const float* __restrict__ img,
                                               const float* __restrict__ bb,
                                               const float* __restrict__ Wb,
                                               const float* __restrict__ Wi,
                                               const float* __restrict__ bi,
                                               const float* __restrict__ Wc,
                                               const float* __restrict__ bc,
                                               const float* __restrict__ Wr,
                                               const float* __restrict__ br,
                                               const float* __restrict__ gt) {
    __shared__ alignas(16) char sbuf[128 * 48 * 4];  // union: wcr2[128][48] f32 | wbs[8192] u16
    __shared__ float red[4][KGT];                    // gtmax reduction
    int t = threadIdx.x;
    int b = blockIdx.x;

    if (b < 1024) {
        // ---- conv1 via MFMA: GEMM M=65536, K=48(pad64), N=128 ----
        unsigned short* wbs = (unsigned short*)sbuf;     // 16 KB staged B
#pragma unroll
        for (int it = 0; it < 4; ++it) {
            int e = t + it * 256;                        // (kt,nt,l)
            int kt = e >> 9, nt = (e >> 6) & 7, l = e & 63;
            unsigned short w8[8];
#pragma unroll
            for (int j = 0; j < 8; ++j) {
                int k = kt * 32 + ((l >> 4) * 8) + j;
                int oc = nt * 16 + (l & 15);
                w8[j] = (k < 48) ? f2b(Wb[(size_t)k * 128 + oc]) : (unsigned short)0;
            }
            *(ulonglong2*)(wbs + (size_t)e * 8) = *(ulonglong2*)w8;
        }
        __syncthreads();

        int cid = ((b & 7) << 7) + (b >> 3);    // XCD swizzle: 1024 % 8 == 0 -> bijective
        int l = t & 63;
        int quad = l >> 4;
        int tile = cid * 4 + (t >> 6);          // 0..4095
        int m0 = tile * 16;
        int p = m0 + (l & 15);
        int oy = p >> 8, ox = p & 255;
        const float* ib = img + ((size_t)oy * 4 * 1024 + (size_t)ox * 4) * 3;

        bf16x8 a0 = ld_a8(ib, quad * 8);
        bf16x8 a1 = (quad < 2) ? ld_a8(ib, 32 + quad * 8) : (bf16x8){0, 0, 0, 0, 0, 0, 0, 0};

        f32x4 acc[8];
#pragma unroll
        for (int nt = 0; nt < 8; ++nt) acc[nt] = (f32x4){0.0f, 0.0f, 0.0f, 0.0f};
#pragma unroll
        for (int nt = 0; nt < 8; ++nt) {
            bf16x8 b0 = *(const bf16x8*)(wbs + (size_t)(nt * 64 + l) * 8);
            bf16x8 b1 = *(const bf16x8*)(wbs + (size_t)((8 + nt) * 64 + l) * 8);
            acc[nt] = __builtin_amdgcn_mfma_f32_16x16x32_bf16(a0, b0, acc[nt], 0, 0, 0);
            acc[nt] = __builtin_amdgcn_mfma_f32_16x16x32_bf16(a1, b1, acc[nt], 0, 0, 0);
        }

        int n0 = l & 15;
        int mB = m0 + quad * 4;
#pragma unroll
        for (int nt = 0; nt < 8; ++nt) {
            int oc = nt * 16 + n0;
            float bias = bb[oc];
#pragma unroll
            for (int r = 0; r < 4; ++r) {
                g_feats[(size_t)(mB + r) * 128 + oc] = f2b(acc[nt][r] + bias);
            }
        }
        return;
    }

    if (b < 1312) {
        // ---- W2 combine, two 128-oc passes ----
        float (*wcr2)[48] = (float (*)[48])sbuf;     // [128][48]
        int bw = b - 1024;
        int wave = __builtin_amdgcn_readfirstlane(t >> 6);
        int lane = t & 63;
        int k = bw * 4 + wave;                       // 0..1151
        int o = min(lane, 47);
        const float* wik = Wi + (size_t)k * 256;
        float acc = 0.0f;
        bool bias_thr = (b == 1024) && (t < 48);
        float a2 = 0.0f;
        if (bias_thr) a2 = (t < 9) ? bc[t] : ((t < 45) ? br[t - 9] : 0.0f);

        for (int pss = 0; pss < 2; ++pss) {
            __syncthreads();                         // protect previous pass's reads
            int ocb = pss * 128;
            for (int i = t; i < 1152; i += 256) {
                int oc = i / 9;
                wcr2[oc][i % 9] = Wc[(size_t)(ocb + oc) * 9 + i % 9];
            }
            for (int i = t; i < 4608; i += 256) {
                int oc = i / 36;
                wcr2[oc][9 + i % 36] = Wr[(size_t)(ocb + oc) * 36 + i % 36];
            }
            for (int i = t; i < 384; i += 256) wcr2[i / 3][45 + i % 3] = 0.0f;
            __syncthreads();
#pragma unroll 8
            for (int oc = 0; oc < 128; ++oc)
                acc = fmaf(wik[ocb + oc], wcr2[oc][o], acc);
            if (bias_thr) {
                for (int oc = 0; oc < 128; ++oc)
                    a2 = fmaf(bi[ocb + oc], wcr2[oc][t], a2);
            }
        }

        if (lane < 48) {
            int kt = k >> 5, r5 = k & 31, j = r5 & 7, lhi = r5 >> 3;
            int nt = o >> 4, llo = o & 15, l2 = lhi * 16 + llo;
            g_W2s[(size_t)((kt * 3 + nt) * 64 + l2) * 8 + j] = f2b(acc);
        }
        if (bias_thr) g_b2[t] = a2;
        return;
    }

    // ---- gtmax ----
    {
        int bid = b - 1312;
        int a = bid >> 5;             // 0..8
        int blk = bid & 31;
        float hw, hh;
        type_extent(a, &hw, &hh);
        float m16[KGT];
#pragma unroll
        for (int k = 0; k < KGT; ++k) m16[k] = -1.0f;
        for (int pix = blk * 256 + t; pix < NPIX; pix += 32 * 256) {
            int w = pix / F2, h = pix - w * F2;
            float cx = (float)w * (1.0f / 254.0f);
            float cy = (float)h * (1.0f / 254.0f);
            float x1 = cx - hw, y1 = cy - hh, x2 = cx + hw, y2 = cy + hh;
            bool inside = (x1 >= 0.0f) && (y1 >= 0.0f) && (x2 < 1.0f) && (y2 < 1.0f);
            if (__ballot(inside) == 0ull) continue;   // whole wave outside
            if (inside) {
                float v[KGT];
                iou16(x1, y1, x2, y2, gt, v);
#pragma unroll
                for (int k = 0; k < KGT; ++k) m16[k] = fmaxf(m16[k], v[k]);
            }
        }
#pragma unroll
        for (int k = 0; k < KGT; ++k) {
#pragma unroll
            for (int m = 32; m; m >>= 1) m16[k] = fmaxf(m16[k], __shfl_xor(m16[k], m, 64));
        }
        int lane = t & 63, wv = t >> 6;
        if (lane == 0) {
#pragma unroll
            for (int k = 0; k < KGT; ++k) red[wv][k] = m16[k];
        }
        __syncthreads();
        if (t < KGT) {
            float mx = fmaxf(fmaxf(red[0][t], red[1][t]), fmaxf(red[2][t], red[3][t]));
            unsigned u = __float_as_uint(mx);
            unsigned key = (u & 0x80000000u) ? ~u : (u | 0x80000000u);
            atomicMax(&g_keys[t], key);
        }
    }
}

// ---------------- combined conv via MFMA + FUSED loss, 64 px/block ----------------
// R2 body with the M-split halved: 1009 blocks x 64 px (one 16-row MFMA tile
// per wave, acc[3]). Mechanism: the 505-block grid was GRID-limited to ~2
// blocks/CU while LDS (37 KB) allows 4 -> doubling the grid doubles resident
// waves for the latency-bound A-load loop. Per-tile MFMA math is unchanged ->
// per-pixel S values bit-identical; loss partition-exact (each m once).
__global__ __launch_bounds__(256) void k_convC_loss(const float* __restrict__ gt,
                                                    unsigned* __restrict__ out) {
    __shared__ alignas(16) unsigned short Bs[12 * 1536];   // 36 KB; reused as f32 [48][129] (24.8 KB)
    __shared__ float redl[4][4];
    int t = threadIdx.x;
    int b = blockIdx.x;
    // bijective XCD swizzle for nwg=1009 = 8*126 + 1 (m204 formula):
    // q=126, r=1 -> xcd 0 gets 127 cids, xcd>=1 get 126 each
    int xcd = b & 7;
    int cid = (xcd == 0) ? (b >> 3) : (127 + (xcd - 1) * 126 + (b >> 3));
    int l = t & 63;
    int quad = l >> 4;
    int wv = t >> 6;
    int tile = cid * 4 + wv;                   // one 16-row tile per wave
    int m0 = tile * 16;
    int mA0 = min(m0 + (l & 15), NPIX - 1);
    int py0 = mA0 / F2, px0 = mA0 - py0 * F2;

    f32x4 acc[3];
#pragma unroll
    for (int nt = 0; nt < 3; ++nt) acc[nt] = (f32x4){0.0f, 0.0f, 0.0f, 0.0f};

    for (int c = 0; c < 3; ++c) {              // chunk = 12 kt
        __syncthreads();
        {   // cooperative stage: 18432 shorts = 2304 uint4 = 9 x 256
            const uint4* src = (const uint4*)(g_W2s + (size_t)c * 18432);
            uint4* dst = (uint4*)Bs;
#pragma unroll
            for (int j = 0; j < 9; ++j) dst[t + 256 * j] = src[t + 256 * j];
        }
        __syncthreads();
#pragma unroll
        for (int i = 0; i < 12; ++i) {
            int kt = c * 12 + i;
            int pos = kt >> 2, kc = kt & 3;
            int ky = pos / 3, kx = pos - ky * 3;
            const unsigned short* ap0 =
                g_feats + ((size_t)(py0 + ky) * 256 + (px0 + kx)) * 128 + quad * 8 + kc * 32;
            bf16x8 a0 = *(const bf16x8*)ap0;
            const unsigned short* bp = Bs + (size_t)i * 1536 + l * 8;
            bf16x8 b0 = *(const bf16x8*)(bp);
            bf16x8 b1 = *(const bf16x8*)(bp + 512);
            bf16x8 b2v = *(const bf16x8*)(bp + 1024);
            acc[0] = __builtin_amdgcn_mfma_f32_16x16x32_bf16(a0, b0, acc[0], 0, 0, 0);
            acc[1] = __builtin_amdgcn_mfma_f32_16x16x32_bf16(a0, b1, acc[1], 0, 0, 0);
            acc[2] = __builtin_amdgcn_mfma_f32_16x16x32_bf16(a0, b2v, acc[2], 0, 0, 0);
        }
    }

    // ---- stage f32 outputs to LDS (reuse Bs). Layout [n][pl], pl-pad 129 ----
    __syncthreads();                           // all waves done reading Bs
    float (*S)[129] = (float (*)[129])(void*)Bs;
    int n0 = l & 15;
    {
        int plB = wv * 16 + quad * 4;          // 0..63
#pragma unroll
        for (int nt = 0; nt < 3; ++nt) {
            int n = nt * 16 + n0;              // 0..47 (g_b2[45..47] == 0)
            float bias = g_b2[n];
#pragma unroll
            for (int r = 0; r < 4; ++r) S[n][plB + r] = acc[nt][r] + bias;
        }
    }
    __syncthreads();

    // ---- fused loss over this block's 64 pixels x 9 anchor types ----
    int m0b = cid * 64;
    float sb = 0.0f, ss = 0.0f, sx = 0.0f, sp = 0.0f;
    for (int idx = t; idx < 576; idx += 256) {
        int a = idx >> 6;                      // 0..8, wave-uniform (64 | 64)
        int pl = idx & 63;
        int m = m0b + pl;
        float hw, hhf;
        type_extent(a, &hw, &hhf);
        bool inside = false;
        float x1 = 0.0f, y1 = 0.0f, x2 = 0.0f, y2 = 0.0f;
        if (m < NPIX) {
            int pw = m / F2, ph = m - pw * F2;
            float cx = (float)pw * (1.0f / 254.0f);
            float cy = (float)ph * (1.0f / 254.0f);
            x1 = cx - hw; y1 = cy - hhf; x2 = cx + hw; y2 = cy + hhf;
            inside = (x1 >= 0.0f) && (y1 >= 0.0f) && (x2 < 1.0f) && (y2 < 1.0f);
        }
        if (__ballot(inside) == 0ull) continue;
        if (inside) {
            float v[KGT];
            iou16(x1, y1, x2, y2, gt, v);
            float maxi = -1.0f;
            bool best = false;
#pragma unroll
            for (int k = 0; k < KGT; ++k) {
                maxi = fmaxf(maxi, v[k]);
                unsigned e = g_keys[k];
                float gm = __uint_as_float((e & 0x80000000u) ? (e & 0x7FFFFFFFu) : ~e);
                best = best || (v[k] == gm);
            }
            bool ispos = best || (maxi >= 0.5f);
            float c = b2f(f2b(S[a][pl]));      // exact old bf16 store/load round-trip
            float z = ispos ? -c : c;
            sb += fmaxf(z, 0.0f) + log1pf(expf(-fabsf(z))); // softplus(z)
            ss += 1.0f;
            if (ispos) {
                float aa;
                aa = fabsf(b2f(f2b(S[9 + 4 * a + 0][pl]))); sx += (aa < 1.0f) ? 0.5f * aa * aa : aa - 0.5f;
                aa = fabsf(b2f(f2b(S[9 + 4 * a + 1][pl]))); sx += (aa < 1.0f) ? 0.5f * aa * aa : aa - 0.5f;
                aa = fabsf(b2f(f2b(S[9 + 4 * a + 2][pl]))); sx += (aa < 1.0f) ? 0.5f * aa * aa : aa - 0.5f;
                aa = fabsf(b2f(f2b(S[9 + 4 * a + 3][pl]))); sx += (aa < 1.0f) ? 0.5f * aa * aa : aa - 0.5f;
                sp += 1.0f;
            }
        }
    }

#pragma unroll
    for (int mm = 32; mm; mm >>= 1) {
        sb += __shfl_xor(sb, mm, 64);
        ss += __shfl_xor(ss, mm, 64);
        sx += __shfl_xor(sx, mm, 64);
        sp += __shfl_xor(sp, mm, 64);
    }
    int lane = t & 63;
    if (lane == 0) { redl[wv][0] = sb; redl[wv][1] = ss; redl[wv][2] = sx; redl[wv][3] = sp; }
    __syncthreads();
    if (t < 4) {
        float s = redl[0][t] + redl[1][t] + redl[2][t] + redl[3][t];
        atomicAdd(&g_acc[t], s);
    }
    // barrier drains vmcnt -> this block's g_acc atomics are L2-visible before g_done bump
    __syncthreads();
    if (t == 0) {
        unsigned prev = atomicAdd(&g_done, 1u);
        if (prev == 1008u) {                   // last of 1009 blocks finalizes
            float a0 = atomicAdd(&g_acc[0], 0.0f);
            float a1 = atomicAdd(&g_acc[1], 0.0f);
            float a2 = atomicAdd(&g_acc[2], 0.0f);
            float a3 = atomicAdd(&g_acc[3], 0.0f);
            float res = a0 / a1 + a2 / a3;
            unsigned lo = (unsigned)f2b(res);
            unsigned hi = __float_as_uint(res) >> 16;
            out[0] = (hi << 16) | lo;
            // reset ALL cross-call state for the next call
            g_acc[0] = 0.0f; g_acc[1] = 0.0f; g_acc[2] = 0.0f; g_acc[3] = 0.0f;
#pragma unroll
            for (int k = 0; k < KGT; ++k) g_keys[k] = 0x407FFFFFu;
            g_done = 0u;
        }
    }
}

extern "C" void kernel_launch(void* const* d_in, const int* in_sizes, int n_in,
                              void* d_out, int out_size, void* d_ws, size_t ws_size,
                              hipStream_t stream) {
    (void)in_sizes; (void)n_in; (void)out_size; (void)d_ws; (void)ws_size;
    const float* image = (const float*)d_in[0];
    const float* gt    = (const float*)d_in[1];
    const float* Wb    = (const float*)d_in[2];
    const float* bb    = (const float*)d_in[3];
    const float* Wi    = (const float*)d_in[4];
    const float* bi    = (const float*)d_in[5];
    const float* Wc    = (const float*)d_in[6];
    const float* bc    = (const float*)d_in[7];
    const float* Wr    = (const float*)d_in[8];
    const float* br    = (const float*)d_in[9];

    k_front     <<<1600, 256, 0, stream>>>(image, bb, Wb, Wi, bi, Wc, bc, Wr, br, gt);
    k_convC_loss<<<1009, 256, 0, stream>>>(gt, (unsigned*)d_out);
}

// Round 8
// 124.366 us; speedup vs baseline: 1.1932x; 1.1932x over previous
//
#include <hip/hip_runtime.h>

// ---------------- problem constants ----------------
#define F2      254
#define NPIX    (F2 * F2)        // 64516 conv2 output pixels
#define KGT     16
#define GWC     (1.0f / 1024.0f) // gw == gh == 1/IMG

typedef __attribute__((ext_vector_type(8))) short bf16x8;
typedef __attribute__((ext_vector_type(4))) float f32x4;

// ---------------- static device storage ----------------
// g_feats in CHANNEL-SLAB layout: [slab = oc>>3][m = py*256+px][8 channels].
// convC's A-fragment (16 consecutive pixels x 8ch) is then ONE contiguous
// 256 B segment per quad (was: 16 segments 256 B apart -> 4x L2-line
// amplification, the R7-diagnosed convC bottleneck).
__device__ unsigned short g_feats[16 * 65536 * 8];   // bf16, 16.78 MB
__device__ unsigned short g_W2s[36 * 3 * 64 * 8];    // combined conv2 weights, bf16, MFMA-B swizzled
__device__ float          g_b2[48];
// cross-call state: statically initialized for the FIRST call; the finalizing
// block of k_convC_loss resets all three for the NEXT call.
__device__ float          g_acc[4] = {0.0f, 0.0f, 0.0f, 0.0f};
__device__ unsigned       g_keys[KGT] = {
    0x407FFFFFu, 0x407FFFFFu, 0x407FFFFFu, 0x407FFFFFu,
    0x407FFFFFu, 0x407FFFFFu, 0x407FFFFFu, 0x407FFFFFu,
    0x407FFFFFu, 0x407FFFFFu, 0x407FFFFFu, 0x407FFFFFu,
    0x407FFFFFu, 0x407FFFFFu, 0x407FFFFFu, 0x407FFFFFu};   // enc(-1.0f)
__device__ unsigned       g_done = 0u;

__device__ __forceinline__ float b2f(unsigned short h) {
    return __uint_as_float(((unsigned)h) << 16);
}
__device__ __forceinline__ unsigned short f2b(float f) {
    unsigned u = __float_as_uint(f);
    unsigned r = (u + 0x7FFFu + ((u >> 16) & 1u)) >> 16;
    return (unsigned short)r;
}

// ---------------- shared IoU16: ONE inlined expression tree -> bit-exact across callers ----------------
__device__ __forceinline__ void iou16(float x1, float y1, float x2, float y2,
                                      const float* __restrict__ gt, float* __restrict__ v) {
    float s1 = (x2 - x1 + GWC) * (y2 - y1 + GWC);
#pragma unroll
    for (int k = 0; k < KGT; ++k) {
        float gx1 = gt[k * 4 + 0], gy1 = gt[k * 4 + 1];
        float gx2 = gt[k * 4 + 2], gy2 = gt[k * 4 + 3];
        float s2 = (gx2 - gx1 + GWC) * (gy2 - gy1 + GWC);
        float xa = fmaxf(x1, gx1), ya = fmaxf(y1, gy1);
        float xb = fminf(x2, gx2), yb = fminf(y2, gy2);
        float iw = fmaxf(xb - xa + GWC, 0.0f);
        float ih = fmaxf(yb - ya + GWC, 0.0f);
        float inter = iw * ih;
        v[k] = inter / (s1 + s2 - inter);
    }
}

// per-type half extents (uniform within a type-major block)
__device__ __forceinline__ void type_extent(int a, float* hw, float* hh) {
    int ri = a / 3, si = a - ri * 3;
    float rat = (ri == 0) ? 0.5f : (ri == 1) ? 1.0f : 2.0f;
    float scl = (si == 0) ? 0.2f : (si == 1) ? 0.4f : 0.7f;
    float rs = sqrtf(rat);
    *hw = scl * rs * 0.5f;
    *hh = scl / rs * 0.5f;
}

// helper: load 8 consecutive im2col k-values (k-order = r*12+q) of one pixel as bf16x8
__device__ __forceinline__ bf16x8 ld_a8(const float* ib, int kbase) {
    int r0 = kbase / 12, q0 = kbase - r0 * 12;
    unsigned short a8[8];
    float4 f0 = *(const float4*)(ib + (size_t)r0 * 3072 + q0);
    int k4 = kbase + 4;
    int r1 = k4 / 12, q1 = k4 - r1 * 12;
    float4 f1 = *(const float4*)(ib + (size_t)r1 * 3072 + q1);
    a8[0] = f2b(f0.x); a8[1] = f2b(f0.y); a8[2] = f2b(f0.z); a8[3] = f2b(f0.w);
    a8[4] = f2b(f1.x); a8[5] = f2b(f1.y); a8[6] = f2b(f1.z); a8[7] = f2b(f1.w);
    return *(bf16x8*)a8;
}

// ---------------- k_front: conv1(MFMA, in-block Wb stage) + W2 combine + gtmax ----------------
// EXACT R2 structure (measured 125.7 us total): roles in PARALLEL blocks.
// Only change vs R2: conv1 epilogue stores to the slab layout (pure address
// permutation; values bit-identical).
// blocks [0,1024)    : conv1 (per-block Wb LDS stage, XCD-banded)
// blocks [1024,1312) : W2 combine (two 128-oc passes)
// blocks [1312,1600) : gtmax (9 x 32 units)
__global__ __launch_bounds__(256) void k_front(const float* __restrict__ img,
                                               const float* __restrict__ bb,
                                               const float* __restrict__ Wb,
                                               const float* __restrict__ Wi,
                                               const float* __restrict__ bi,
                                               const float* __restrict__ Wc,
                                               const float* __restrict__ bc,
                                               const float* __restrict__ Wr,
                                               const float* __restrict__ br,
                                               const float* __restrict__ gt) {
    __shared__ alignas(16) char sbuf[128 * 48 * 4];  // union: wcr2[128][48] f32 | wbs[8192] u16
    __shared__ float red[4][KGT];                    // gtmax reduction
    int t = threadIdx.x;
    int b = blockIdx.x;

    if (b < 1024) {
        // ---- conv1 via MFMA: GEMM M=65536, K=48(pad64), N=128 ----
        unsigned short* wbs = (unsigned short*)sbuf;     // 16 KB staged B
#pragma unroll
        for (int it = 0; it < 4; ++it) {
            int e = t + it * 256;                        // (kt,nt,l)
            int kt = e >> 9, nt = (e >> 6) & 7, l = e & 63;
            unsigned short w8[8];
#pragma unroll
            for (int j = 0; j < 8; ++j) {
                int k = kt * 32 + ((l >> 4) * 8) + j;
                int oc = nt * 16 + (l & 15);
                w8[j] = (k < 48) ? f2b(Wb[(size_t)k * 128 + oc]) : (unsigned short)0;
            }
            *(ulonglong2*)(wbs + (size_t)e * 8) = *(ulonglong2*)w8;
        }
        __syncthreads();

        int cid = ((b & 7) << 7) + (b >> 3);    // XCD swizzle: 1024 % 8 == 0 -> bijective
        int l = t & 63;
        int quad = l >> 4;
        int tile = cid * 4 + (t >> 6);          // 0..4095
        int m0 = tile * 16;
        int p = m0 + (l & 15);
        int oy = p >> 8, ox = p & 255;
        const float* ib = img + ((size_t)oy * 4 * 1024 + (size_t)ox * 4) * 3;

        bf16x8 a0 = ld_a8(ib, quad * 8);
        bf16x8 a1 = (quad < 2) ? ld_a8(ib, 32 + quad * 8) : (bf16x8){0, 0, 0, 0, 0, 0, 0, 0};

        f32x4 acc[8];
#pragma unroll
        for (int nt = 0; nt < 8; ++nt) acc[nt] = (f32x4){0.0f, 0.0f, 0.0f, 0.0f};
#pragma unroll
        for (int nt = 0; nt < 8; ++nt) {
            bf16x8 b0 = *(const bf16x8*)(wbs + (size_t)(nt * 64 + l) * 8);
            bf16x8 b1 = *(const bf16x8*)(wbs + (size_t)((8 + nt) * 64 + l) * 8);
            acc[nt] = __builtin_amdgcn_mfma_f32_16x16x32_bf16(a0, b0, acc[nt], 0, 0, 0);
            acc[nt] = __builtin_amdgcn_mfma_f32_16x16x32_bf16(a1, b1, acc[nt], 0, 0, 0);
        }

        int n0 = l & 15;
        int mB = m0 + quad * 4;
#pragma unroll
        for (int nt = 0; nt < 8; ++nt) {
            int oc = nt * 16 + n0;
            float bias = bb[oc];
            int slab = oc >> 3;                 // 0..15
            int ch = oc & 7;
#pragma unroll
            for (int r = 0; r < 4; ++r) {
                g_feats[((size_t)slab * 65536 + (mB + r)) * 8 + ch] = f2b(acc[nt][r] + bias);
            }
        }
        return;
    }

    if (b < 1312) {
        // ---- W2 combine, two 128-oc passes ----
        float (*wcr2)[48] = (float (*)[48])sbuf;     // [128][48]
        int bw = b - 1024;
        int wave = __builtin_amdgcn_readfirstlane(t >> 6);
        int lane = t & 63;
        int k = bw * 4 + wave;                       // 0..1151
        int o = min(lane, 47);
        const float* wik = Wi + (size_t)k * 256;
        float acc = 0.0f;
        bool bias_thr = (b == 1024) && (t < 48);
        float a2 = 0.0f;
        if (bias_thr) a2 = (t < 9) ? bc[t] : ((t < 45) ? br[t - 9] : 0.0f);

        for (int pss = 0; pss < 2; ++pss) {
            __syncthreads();                         // protect previous pass's reads
            int ocb = pss * 128;
            for (int i = t; i < 1152; i += 256) {
                int oc = i / 9;
                wcr2[oc][i % 9] = Wc[(size_t)(ocb + oc) * 9 + i % 9];
            }
            for (int i = t; i < 4608; i += 256) {
                int oc = i / 36;
                wcr2[oc][9 + i % 36] = Wr[(size_t)(ocb + oc) * 36 + i % 36];
            }
            for (int i = t; i < 384; i += 256) wcr2[i / 3][45 + i % 3] = 0.0f;
            __syncthreads();
#pragma unroll 8
            for (int oc = 0; oc < 128; ++oc)
                acc = fmaf(wik[ocb + oc], wcr2[oc][o], acc);
            if (bias_thr) {
                for (int oc = 0; oc < 128; ++oc)
                    a2 = fmaf(bi[ocb + oc], wcr2[oc][t], a2);
            }
        }

        if (lane < 48) {
            int kt = k >> 5, r5 = k & 31, j = r5 & 7, lhi = r5 >> 3;
            int nt = o >> 4, llo = o & 15, l2 = lhi * 16 + llo;
            g_W2s[(size_t)((kt * 3 + nt) * 64 + l2) * 8 + j] = f2b(acc);
        }
        if (bias_thr) g_b2[t] = a2;
        return;
    }

    // ---- gtmax ----
    {
        int bid = b - 1312;
        int a = bid >> 5;             // 0..8
        int blk = bid & 31;
        float hw, hh;
        type_extent(a, &hw, &hh);
        float m16[KGT];
#pragma unroll
        for (int k = 0; k < KGT; ++k) m16[k] = -1.0f;
        for (int pix = blk * 256 + t; pix < NPIX; pix += 32 * 256) {
            int w = pix / F2, h = pix - w * F2;
            float cx = (float)w * (1.0f / 254.0f);
            float cy = (float)h * (1.0f / 254.0f);
            float x1 = cx - hw, y1 = cy - hh, x2 = cx + hw, y2 = cy + hh;
            bool inside = (x1 >= 0.0f) && (y1 >= 0.0f) && (x2 < 1.0f) && (y2 < 1.0f);
            if (__ballot(inside) == 0ull) continue;   // whole wave outside
            if (inside) {
                float v[KGT];
                iou16(x1, y1, x2, y2, gt, v);
#pragma unroll
                for (int k = 0; k < KGT; ++k) m16[k] = fmaxf(m16[k], v[k]);
            }
        }
#pragma unroll
        for (int k = 0; k < KGT; ++k) {
#pragma unroll
            for (int m = 32; m; m >>= 1) m16[k] = fmaxf(m16[k], __shfl_xor(m16[k], m, 64));
        }
        int lane = t & 63, wv = t >> 6;
        if (lane == 0) {
#pragma unroll
            for (int k = 0; k < KGT; ++k) red[wv][k] = m16[k];
        }
        __syncthreads();
        if (t < KGT) {
            float mx = fmaxf(fmaxf(red[0][t], red[1][t]), fmaxf(red[2][t], red[3][t]));
            unsigned u = __float_as_uint(mx);
            unsigned key = (u & 0x80000000u) ? ~u : (u | 0x80000000u);
            atomicMax(&g_keys[t], key);
        }
    }
}

// ---------------- combined conv via MFMA + FUSED loss (proven R2 505-block body) ----------------
// Only change vs R2: A-loads read the slab layout -> each quad's 16 lanes read
// ONE contiguous 256 B segment (was 16 x 16 B at 256 B stride = 4x L2-line
// amplification). Values bit-identical.
__global__ __launch_bounds__(256) void k_convC_loss(const float* __restrict__ gt,
                                                    unsigned* __restrict__ out) {
    __shared__ alignas(16) unsigned short Bs[12 * 1536];   // 36 KB; reused as f32 [48][129]
    __shared__ float redl[4][4];
    int t = threadIdx.x;
    int b = blockIdx.x;
    // bijective XCD swizzle for nwg=505 = 8*63 + 1 (m204 formula)
    int xcd = b & 7;
    int cid = (xcd == 0) ? (b >> 3) : (64 + (xcd - 1) * 63 + (b >> 3));
    int l = t & 63;
    int quad = l >> 4;
    int wv = t >> 6;
    int tile = cid * 4 + wv;
    int m0 = tile * 32;
    int mA0 = min(m0 + (l & 15), NPIX - 1);
    int mA1 = min(m0 + 16 + (l & 15), NPIX - 1);
    int py0 = mA0 / F2, px0 = mA0 - py0 * F2;
    int py1 = mA1 / F2, px1 = mA1 - py1 * F2;

    f32x4 acc[2][3];
#pragma unroll
    for (int h = 0; h < 2; ++h)
#pragma unroll
        for (int nt = 0; nt < 3; ++nt) acc[h][nt] = (f32x4){0.0f, 0.0f, 0.0f, 0.0f};

    for (int c = 0; c < 3; ++c) {              // chunk = 12 kt
        __syncthreads();
        {   // cooperative stage: 18432 shorts = 2304 uint4 = 9 x 256
            const uint4* src = (const uint4*)(g_W2s + (size_t)c * 18432);
            uint4* dst = (uint4*)Bs;
#pragma unroll
            for (int j = 0; j < 9; ++j) dst[t + 256 * j] = src[t + 256 * j];
        }
        __syncthreads();
#pragma unroll
        for (int i = 0; i < 12; ++i) {
            int kt = c * 12 + i;
            int pos = kt >> 2, kc = kt & 3;
            int ky = pos / 3, kx = pos - ky * 3;
            int slab = kc * 4 + quad;          // channel block (quad*8 + kc*32) >> 3
            const unsigned short* ap0 =
                g_feats + ((size_t)slab * 65536 + ((py0 + ky) * 256 + (px0 + kx))) * 8;
            const unsigned short* ap1 =
                g_feats + ((size_t)slab * 65536 + ((py1 + ky) * 256 + (px1 + kx))) * 8;
            bf16x8 a0 = *(const bf16x8*)ap0;
            bf16x8 a1 = *(const bf16x8*)ap1;
            const unsigned short* bp = Bs + (size_t)i * 1536 + l * 8;
            bf16x8 b0 = *(const bf16x8*)(bp);
            bf16x8 b1 = *(const bf16x8*)(bp + 512);
            bf16x8 b2v = *(const bf16x8*)(bp + 1024);
            acc[0][0] = __builtin_amdgcn_mfma_f32_16x16x32_bf16(a0, b0, acc[0][0], 0, 0, 0);
            acc[0][1] = __builtin_amdgcn_mfma_f32_16x16x32_bf16(a0, b1, acc[0][1], 0, 0, 0);
            acc[0][2] = __builtin_amdgcn_mfma_f32_16x16x32_bf16(a0, b2v, acc[0][2], 0, 0, 0);
            acc[1][0] = __builtin_amdgcn_mfma_f32_16x16x32_bf16(a1, b0, acc[1][0], 0, 0, 0);
            acc[1][1] = __builtin_amdgcn_mfma_f32_16x16x32_bf16(a1, b1, acc[1][1], 0, 0, 0);
            acc[1][2] = __builtin_amdgcn_mfma_f32_16x16x32_bf16(a1, b2v, acc[1][2], 0, 0, 0);
        }
    }

    // ---- stage f32 outputs to LDS (reuse Bs). Layout [n][pl] with pl-pad 129 ----
    __syncthreads();                           // all waves done reading Bs
    float (*S)[129] = (float (*)[129])(void*)Bs;
    int n0 = l & 15;
#pragma unroll
    for (int h = 0; h < 2; ++h) {
        int plB = wv * 32 + h * 16 + quad * 4;
#pragma unroll
        for (int nt = 0; nt < 3; ++nt) {
            int n = nt * 16 + n0;              // 0..47 (g_b2[45..47] == 0)
            float bias = g_b2[n];
#pragma unroll
            for (int r = 0; r < 4; ++r) S[n][plB + r] = acc[h][nt][r] + bias;
        }
    }
    __syncthreads();

    // ---- fused loss over this block's 128 pixels x 9 anchor types ----
    int m0b = cid * 128;
    float sb = 0.0f, ss = 0.0f, sx = 0.0f, sp = 0.0f;
    for (int idx = t; idx < 1152; idx += 256) {
        int a = idx >> 7;                      // a-major: wave-uniform type
        int pl = idx & 127;
        int m = m0b + pl;
        float hw, hhf;
        type_extent(a, &hw, &hhf);
        bool inside = false;
        float x1 = 0.0f, y1 = 0.0f, x2 = 0.0f, y2 = 0.0f;
        if (m < NPIX) {
            int pw = m / F2, ph = m - pw * F2;
            float cx = (float)pw * (1.0f / 254.0f);
            float cy = (float)ph * (1.0f / 254.0f);
            x1 = cx - hw; y1 = cy - hhf; x2 = cx + hw; y2 = cy + hhf;
            inside = (x1 >= 0.0f) && (y1 >= 0.0f) && (x2 < 1.0f) && (y2 < 1.0f);
        }
        if (__ballot(inside) == 0ull) continue;
        if (inside) {
            float v[KGT];
            iou16(x1, y1, x2, y2, gt, v);
            float maxi = -1.0f;
            bool best = false;
#pragma unroll
            for (int k = 0; k < KGT; ++k) {
                maxi = fmaxf(maxi, v[k]);
                unsigned e = g_keys[k];
                float gm = __uint_as_float((e & 0x80000000u) ? (e & 0x7FFFFFFFu) : ~e);
                best = best || (v[k] == gm);
            }
            bool ispos = best || (maxi >= 0.5f);
            float c = b2f(f2b(S[a][pl]));      // exact old bf16 store/load round-trip
            float z = ispos ? -c : c;
            sb += fmaxf(z, 0.0f) + log1pf(expf(-fabsf(z))); // softplus(z)
            ss += 1.0f;
            if (ispos) {
                float aa;
                aa = fabsf(b2f(f2b(S[9 + 4 * a + 0][pl]))); sx += (aa < 1.0f) ? 0.5f * aa * aa : aa - 0.5f;
                aa = fabsf(b2f(f2b(S[9 + 4 * a + 1][pl]))); sx += (aa < 1.0f) ? 0.5f * aa * aa : aa - 0.5f;
                aa = fabsf(b2f(f2b(S[9 + 4 * a + 2][pl]))); sx += (aa < 1.0f) ? 0.5f * aa * aa : aa - 0.5f;
                aa = fabsf(b2f(f2b(S[9 + 4 * a + 3][pl]))); sx += (aa < 1.0f) ? 0.5f * aa * aa : aa - 0.5f;
                sp += 1.0f;
            }
        }
    }

#pragma unroll
    for (int mm = 32; mm; mm >>= 1) {
        sb += __shfl_xor(sb, mm, 64);
        ss += __shfl_xor(ss, mm, 64);
        sx += __shfl_xor(sx, mm, 64);
        sp += __shfl_xor(sp, mm, 64);
    }
    int lane = t & 63;
    if (lane == 0) { redl[wv][0] = sb; redl[wv][1] = ss; redl[wv][2] = sx; redl[wv][3] = sp; }
    __syncthreads();
    if (t < 4) {
        float s = redl[0][t] + redl[1][t] + redl[2][t] + redl[3][t];
        atomicAdd(&g_acc[t], s);
    }
    // barrier drains vmcnt -> this block's g_acc atomics are L2-visible before g_done bump
    __syncthreads();
    if (t == 0) {
        unsigned prev = atomicAdd(&g_done, 1u);
        if (prev == 504u) {                    // last of 505 blocks finalizes
            float a0 = atomicAdd(&g_acc[0], 0.0f);
            float a1 = atomicAdd(&g_acc[1], 0.0f);
            float a2 = atomicAdd(&g_acc[2], 0.0f);
            float a3 = atomicAdd(&g_acc[3], 0.0f);
            float res = a0 / a1 + a2 / a3;
            unsigned lo = (unsigned)f2b(res);
            unsigned hi = __float_as_uint(res) >> 16;
            out[0] = (hi << 16) | lo;
            // reset ALL cross-call state for the next call
            g_acc[0] = 0.0f; g_acc[1] = 0.0f; g_acc[2] = 0.0f; g_acc[3] = 0.0f;
#pragma unroll
            for (int k = 0; k < KGT; ++k) g_keys[k] = 0x407FFFFFu;
            g_done = 0u;
        }
    }
}

extern "C" void kernel_launch(void* const* d_in, const int* in_sizes, int n_in,
                              void* d_out, int out_size, void* d_ws, size_t ws_size,
                              hipStream_t stream) {
    (void)in_sizes; (void)n_in; (void)out_size; (void)d_ws; (void)ws_size;
    const float* image = (const float*)d_in[0];
    const float* gt    = (const float*)d_in[1];
    const float* Wb    = (const float*)d_in[2];
    const float* bb    = (const float*)d_in[3];
    const float* Wi    = (const float*)d_in[4];
    const float* bi    = (const float*)d_in[5];
    const float* Wc    = (const float*)d_in[6];
    const float* bc    = (const float*)d_in[7];
    const float* Wr    = (const float*)d_in[8];
    const float* br    = (const float*)d_in[9];

    k_front     <<<1600, 256, 0, stream>>>(image, bb, Wb, Wi, bi, Wc, bc, Wr, br, gt);
    k_convC_loss<<<505, 256, 0, stream>>>(gt, (unsigned*)d_out);
}